// Round 8
// baseline (178.989 us; speedup 1.0000x reference)
//
#include <hip/hip_runtime.h>
#include <hip/hip_bf16.h>

// TopoGraphLayer: B=1024, NJ=16, NW=2, NT=2, D=128, H=128
// R8: k_fused is A-build VALU-bound (R7 counters: 66K VALU cyc/CU vs 17K MFMA).
// Cut VALU/elem: U/V stay f32 in LDS (no unpack), v_cvt_pk_bf16_f32 packs the
// relu'd pair in 1 inst. 1 batch/wg (57.3KB LDS), grid 1024.

using short4v = __attribute__((ext_vector_type(4))) short;
using short8 = __attribute__((ext_vector_type(8))) short;
using f32x4  = __attribute__((ext_vector_type(4))) float;
using u32x4  = __attribute__((ext_vector_type(4))) unsigned;

#define DEVI __device__ __forceinline__

DEVI float b2f(short s){
  unsigned u = ((unsigned)(unsigned short)s) << 16;
  float f; __builtin_memcpy(&f, &u, 4); return f;
}
DEVI short f2b(float f){
  __hip_bfloat16 h = __float2bfloat16(f);
  short s; __builtin_memcpy(&s, &h, 2); return s;
}
DEVI unsigned cvtpk(float lo, float hi){
  unsigned r;
  asm("v_cvt_pk_bf16_f32 %0, %1, %2" : "=v"(r) : "v"(lo), "v"(hi));
  return r;
}
DEVI float ldflex(const void* p, long i, int bf){
  return bf ? b2f(((const short*)p)[i]) : ((const float*)p)[i];
}
DEVI f32x4 mfma16(short8 a, short8 b, f32x4 c){
  return __builtin_amdgcn_mfma_f32_16x16x32_bf16(a, b, c, 0, 0, 0);
}

// ---------------- ws byte offsets ----------------
constexpr size_t OF_MASKF  = 256;
constexpr size_t OF_INVCNT = 65792;
constexpr size_t OF_XJ     = 69888;
constexpr size_t OF_XW     = 4264192;
constexpr size_t OF_XT     = 4788480;
constexpr size_t OF_W1T    = 5312768;   // bf16 [7][128][256]
constexpr size_t OF_W2T    = 5771520;   // bf16 [7][128][128]
constexpr size_t OF_EB1F   = 6000896;
constexpr size_t OF_EB2F   = 6004480;
constexpr size_t OF_JW1T   = 6008064;   // bf16 [128][512]
constexpr size_t OF_JW2T   = 6139136;   // bf16 [128][128]
constexpr size_t OF_JB1F   = 6171904;
constexpr size_t OF_JB2F   = 6172416;
constexpr size_t OF_WTW1T  = 6172928;   // bf16 [2][128][384]
constexpr size_t OF_WTW2T  = 6369536;   // bf16 [2][128][128]
constexpr size_t OF_WTB1F  = 6435072;
constexpr size_t OF_WTB2F  = 6436096;
constexpr size_t OF_POOL   = 65157376;  // bf16, 7,340,032 elems

// jobs: job = net*2 + half (half0=src gets bias). PJ_SRC: 0=J,1=W,2=T
__constant__ int PJ_SRC[14] = {0,0,0,1,0,2,1,0,1,2,2,0,2,1};
__constant__ int IS_J[14]   = {1,1,1,0,1,0,0,1,0,0,0,1,0,0};
// LDS UV row base per job (112 rows total; J jobs 16 rows, WT 2)
__constant__ int JOB_BASE[14] = {0,16,32,96,48,98,100,64,102,104,106,80,108,110};
// proj schedule per wave-pair
__constant__ int PS_JOB[4][4] = {{0,1,3,5},{2,4,6,8},{7,11,9,9},{10,12,13,13}};
__constant__ int PS_CNT[4] = {4,4,3,3};
// edge schedule per wave-pair
__constant__ int ES_NET[4][7] = {
 {0,0,0,0,1,1,4},
 {0,0,0,0,2,2,6},
 {0,0,0,0,3,3,0},
 {0,0,0,0,5,5,0}};
__constant__ int ES_EB[4][7] = {
 {0,16,32,48, 0,16, 0},
 {64,80,96,112, 0,16, 0},
 {128,144,160,176, 0,16, 0},
 {192,208,224,240, 0,16, 0}};
__constant__ int ES_CNT[4] = {7,7,6,6};
__constant__ int EN_LGND[7] = {4,1,1,4,1,4,1};
__constant__ int EN_NS[7]   = {16,16,16,2,2,2,2};
__constant__ long long EN_POOL[7] = {0,2097152,4194304,6291456,6553600,6815744,7077888};
// transpose jobs
__constant__ int TJ_CUM[21] = {0,32,64,96,128,160,192,224,240,256,272,288,304,320,336,400,416,464,512,528,544};
__constant__ int TJ_SEL[20] = {0,0,0,0,0,0,0,1,1,1,1,1,1,1,2,3,4,4,5,5};
__constant__ int TJ_OFF[20] = {0,32768,65536,98304,131072,163840,196608,
                               0,16384,32768,49152,65536,81920,98304,
                               0,0,0,49152,0,16384};
__constant__ int TJ_R[20]   = {256,256,256,256,256,256,256,128,128,128,128,128,128,128,512,128,384,384,128,128};

// -------- probe: detect float dtype (f32 vs bf16) and mask format --------
__global__ __launch_bounds__(64) void k_probe(const void* jets, const void* mask, int* flags){
  int l = threadIdx.x;
  int extreme = 0;
  #pragma unroll
  for(int s=0;s<4;s++){
    unsigned short v = ((const unsigned short*)jets)[(l*4+s)*2];
    int e = (v>>7)&0xff;
    if(e<110||e>140) extreme++;
  }
  #pragma unroll
  for(int o=1;o<64;o<<=1) extreme += __shfl_xor(extreme, o);
  bool all01=true, allf32=true;
  #pragma unroll
  for(int s=0;s<4;s++){
    unsigned w = ((const unsigned*)mask)[l*4+s];
    if(w>1u) all01=false;
    if(w!=0u && w!=0x3F800000u) allf32=false;
  }
  bool allbfv=true; int evnz=0;
  #pragma unroll
  for(int s=0;s<8;s++){
    unsigned short v = ((const unsigned short*)mask)[l*8+s];
    if(v!=0&&v!=0x3F80) allbfv=false;
    if(((l*8+s)&1)==0 && v!=0) evnz++;
  }
  #pragma unroll
  for(int o=1;o<64;o<<=1) evnz += __shfl_xor(evnz, o);
  bool allb01=true;
  #pragma unroll
  for(int s=0;s<16;s++){ if(((const unsigned char*)mask)[l*16+s]>1) allb01=false; }
  int a01 = __all(all01), af32 = __all(allf32), abf = __all(allbfv), ab01 = __all(allb01);
  if(l==0){
    flags[0] = (extreme <= 32) ? 1 : 0;   // 1=bf16 inputs, 0=f32
    int fmt = 0;
    if(a01) fmt=0; else if(abf && evnz>0) fmt=2; else if(af32) fmt=3; else if(ab01) fmt=1;
    flags[1] = fmt;
  }
}

// -------- maskf + invcnt + biases (merged) --------
__global__ __launch_bounds__(256) void k_maskbias(const void* mask, const int* flags,
    float* maskf, float* invcnt,
    const void* eb1, const void* eb2, const void* jb1, const void* jb2,
    const void* wb1, const void* wb2,
    float* EB1F, float* EB2F, float* JB1F, float* JB2F, float* WTB1F, float* WTB2F){
  int bid = blockIdx.x;
  if(bid < 64){
    int t = bid*256 + threadIdx.x;  // 0..16383
    int fmt = flags[1];
    float m;
    if(fmt==0)      m = (((const int*)mask)[t]!=0) ? 1.f : 0.f;
    else if(fmt==1) m = (((const unsigned char*)mask)[t]!=0) ? 1.f : 0.f;
    else if(fmt==2) m = (b2f(((const short*)mask)[t])!=0.f) ? 1.f : 0.f;
    else            m = (((const float*)mask)[t]!=0.f) ? 1.f : 0.f;
    maskf[t] = m;
    float s = m;
    for(int o=1;o<16;o<<=1) s += __shfl_xor(s, o);
    if((t&15)==0) invcnt[t>>4] = 1.f / fmaxf(s, 1.f);
  } else {
    int id = (bid-64)*256 + threadIdx.x;
    int bf = flags[0];
    if(id<896)        EB1F[id]       = ldflex(eb1, id, bf);
    else if(id<1792)  EB2F[id-896]   = ldflex(eb2, id-896, bf);
    else if(id<1920)  JB1F[id-1792]  = ldflex(jb1, id-1792, bf);
    else if(id<2048)  JB2F[id-1920]  = ldflex(jb2, id-1920, bf);
    else if(id<2304)  WTB1F[id-2048] = ldflex(wb1, id-2048, bf);
    else if(id<2560)  WTB2F[id-2304] = ldflex(wb2, id-2304, bf);
  }
}

// -------- convert node inputs to canonical bf16 (x4 vectorized) --------
__global__ __launch_bounds__(256) void k_convx(const void* jets, const void* nw, const void* nt,
                                               const int* flags, short* XJ, short* XW, short* XT){
  long i = ((long)blockIdx.x*256 + threadIdx.x)*4;
  int bf = flags[0];
  const void* src; short* dst; long o;
  if(i < 2097152){ src=jets; dst=XJ; o=i; }
  else if(i < 2359296){ src=nw; dst=XW; o=i-2097152; }
  else { src=nt; dst=XT; o=i-2359296; }
  short4v r;
  if(bf){
    r = *(const short4v*)((const short*)src + o);
  } else {
    f32x4 v = *(const f32x4*)((const float*)src + o);
    #pragma unroll
    for(int e=0;e<4;e++) r[e] = f2b(v[e]);
  }
  *(short4v*)(dst + o) = r;
}

// -------- weight transpose via LDS 32x32 tiles --------
__global__ __launch_bounds__(256) void k_trans(const void* eW1, const void* eW2, const void* jW1,
    const void* jW2, const void* wW1, const void* wW2, const int* flags,
    short* W1T, short* W2T, short* JW1T, short* JW2T, short* WTW1T, short* WTW2T){
  __shared__ float tl[32][33];
  int tile = blockIdx.x; int job = 0;
  while(tile >= TJ_CUM[job+1]) job++;
  tile -= TJ_CUM[job];
  int sel = TJ_SEL[job]; long off = TJ_OFF[job]; int R = TJ_R[job];
  int bf = flags[0];
  const void* src = sel==0?eW1: sel==1?eW2: sel==2?jW1: sel==3?jW2: sel==4?wW1: wW2;
  short* dst = sel==0?W1T: sel==1?W2T: sel==2?JW1T: sel==3?JW2T: sel==4?WTW1T: WTW2T;
  int tr = (tile>>2)*32, tc = (tile&3)*32;
  int t = threadIdx.x, r = t>>3, c4 = (t&7)*4;
  #pragma unroll
  for(int j=0;j<4;j++) tl[r][c4+j] = ldflex(src, off + (long)(tr+r)*128 + tc + c4 + j, bf);
  __syncthreads();
  short4v o;
  #pragma unroll
  for(int j=0;j<4;j++) o[j] = f2b(tl[c4+j][r]);
  *(short4v*)(dst + off + (long)(tc+r)*R + tr + c4) = o;
}

// -------- FUSED proj + edge + pool: wg = 1 batch, 8 waves (4 pairs) --------
// LDS UV[112][128] f32, swizzle: byte ^= (row&7)<<4 (16B granular).
__global__ __launch_bounds__(512, 4) void k_fused(const short* XJ, const short* XW, const short* XT,
    const short* W1T, const short* W2T, const float* EB1F, const float* EB2F,
    const float* maskf, const float* invcnt, short* POOL){
  __shared__ float UVs[14336];   // 112 x 128 f32 = 57,344 B
  long b = blockIdx.x;
  int t = threadIdx.x, lane = t & 63, wv = t >> 6;
  int pair = wv >> 1, h = wv & 1;
  int cl = lane & 15, kh = lane >> 4;

  // ---------------- projection phase ----------------
  int pcnt = PS_CNT[pair];
  for(int slot=0; slot<pcnt; slot++){
    int job = PS_JOB[pair][slot];
    int net = job>>1, half = job&1;
    int isj = IS_J[job];
    const short* Wb = W1T + net*32768 + half*128;
    short8 bw[4][4];
    #pragma unroll
    for(int nt=0;nt<4;nt++)
      #pragma unroll
      for(int ks=0;ks<4;ks++)
        bw[nt][ks] = *(const short8*)(Wb + (h*64 + nt*16 + cl)*256 + ks*32 + kh*8);
    const short* X; long xrow; int ldsrow;
    if(isj){
      X = XJ; xrow = b*16 + cl; ldsrow = JOB_BASE[job] + cl;
    } else {
      X = (PJ_SRC[job]==1) ? XW : XT;
      xrow = b*2 + (cl&1); ldsrow = JOB_BASE[job] + (cl&1);
    }
    short8 a[4];
    #pragma unroll
    for(int ks=0;ks<4;ks++)
      a[ks] = *(const short8*)(X + xrow*128 + ks*32 + kh*8);
    f32x4 acc[4] = {};
    #pragma unroll
    for(int ks=0;ks<4;ks++)
      #pragma unroll
      for(int nt=0;nt<4;nt++)
        acc[nt] = mfma16(bw[nt][ks], a[ks], acc[nt]);   // D: col=xrow(cl), row=c-block
    if(isj || cl < 2){
      int swz = (ldsrow&7)<<4;
      #pragma unroll
      for(int nt=0;nt<4;nt++){
        f32x4 fv;
        if(half==0){
          f32x4 bv = *(const f32x4*)(EB1F + net*128 + h*64 + nt*16 + kh*4);
          #pragma unroll
          for(int r=0;r<4;r++) fv[r] = acc[nt][r] + bv[r];
        } else fv = acc[nt];
        *(f32x4*)((char*)UVs + ((ldsrow*512 + h*256 + nt*64 + kh*16) ^ swz)) = fv;
      }
    }
  }
  __syncthreads();

  // ---------------- edge + pool phase ----------------
  int prevnet = -1;
  short8 bw[4][4];
  float bias[4];
  int cnt = ES_CNT[pair];
  for(int slot=0; slot<cnt; slot++){
    int net = ES_NET[pair][slot];
    int eb  = ES_EB[pair][slot];
    if(net != prevnet){
      const short* Wb2 = W2T + net*16384;
      #pragma unroll
      for(int nt=0;nt<4;nt++){
        #pragma unroll
        for(int ks=0;ks<4;ks++)
          bw[nt][ks] = *(const short8*)(Wb2 + (h*64 + nt*16 + cl)*128 + ks*32 + kh*8);
        bias[nt] = EB2F[net*128 + h*64 + nt*16 + cl];
      }
      prevnet = net;
    }
    int lgNd = EN_LGND[net];
    int tiny = (net==4) | (net==6);
    int sj = JOB_BASE[2*net], dj = JOB_BASE[2*net+1];
    int e = tiny ? (cl&3) : (eb + cl);
    int urow = sj + (e >> lgNd);
    int vrow = dj + (e & ((1<<lgNd)-1));
    int uswz = (urow&7)<<4, vswz = (vrow&7)<<4;
    f32x4 acc[4] = {};
    #pragma unroll
    for(int ks=0;ks<4;ks++){
      int ubase = urow*512 + ks*128 + kh*32;
      int vbase = vrow*512 + ks*128 + kh*32;
      f32x4 u0 = *(const f32x4*)((const char*)UVs + (ubase ^ uswz));
      f32x4 u1 = *(const f32x4*)((const char*)UVs + ((ubase+16) ^ uswz));
      f32x4 v0 = *(const f32x4*)((const char*)UVs + (vbase ^ vswz));
      f32x4 v1 = *(const f32x4*)((const char*)UVs + ((vbase+16) ^ vswz));
      u32x4 aw;
      aw[0] = cvtpk(fmaxf(u0[0]+v0[0],0.f), fmaxf(u0[1]+v0[1],0.f));
      aw[1] = cvtpk(fmaxf(u0[2]+v0[2],0.f), fmaxf(u0[3]+v0[3],0.f));
      aw[2] = cvtpk(fmaxf(u1[0]+v1[0],0.f), fmaxf(u1[1]+v1[1],0.f));
      aw[3] = cvtpk(fmaxf(u1[2]+v1[2],0.f), fmaxf(u1[3]+v1[3],0.f));
      short8 a = __builtin_bit_cast(short8, aw);
      #pragma unroll
      for(int nt=0;nt<4;nt++)
        acc[nt] = mfma16(a, bw[nt][ks], acc[nt]);   // D: row=edge row, col=w2 col
    }
    short* pool = POOL + EN_POOL[net];
    int Ns = EN_NS[net];
    if(tiny){
      if(kh == 0){
        #pragma unroll
        for(int nt=0;nt<4;nt++){
          int col = h*64 + nt*16 + cl;
          float v0 = fmaxf(acc[nt][0]+bias[nt],0.f);
          float v1 = fmaxf(acc[nt][1]+bias[nt],0.f);
          float v2 = fmaxf(acc[nt][2]+bias[nt],0.f);
          float v3 = fmaxf(acc[nt][3]+bias[nt],0.f);
          long pr = b*2;
          pool[pr*128 + col]     = f2b((v0+v1)*0.5f);
          pool[(pr+1)*128 + col] = f2b((v2+v3)*0.5f);
        }
      }
    } else if(lgNd == 4){
      float ic = invcnt[b];
      float wr[4];
      #pragma unroll
      for(int r=0;r<4;r++)
        wr[r] = maskf[b*16 + kh*4 + r] * ic;
      #pragma unroll
      for(int nt=0;nt<4;nt++){
        int col = h*64 + nt*16 + cl;
        float s = fmaxf(acc[nt][0]+bias[nt],0.f)*wr[0]
                + fmaxf(acc[nt][1]+bias[nt],0.f)*wr[1]
                + fmaxf(acc[nt][2]+bias[nt],0.f)*wr[2]
                + fmaxf(acc[nt][3]+bias[nt],0.f)*wr[3];
        s += __shfl_xor(s, 16);
        s += __shfl_xor(s, 32);
        if(lane < 16)
          pool[(b*Ns + (eb>>4))*128 + col] = f2b(s);
      }
    } else {
      long i0 = (eb + kh*4) >> 1;
      #pragma unroll
      for(int nt=0;nt<4;nt++){
        int col = h*64 + nt*16 + cl;
        float v0 = fmaxf(acc[nt][0]+bias[nt],0.f);
        float v1 = fmaxf(acc[nt][1]+bias[nt],0.f);
        float v2 = fmaxf(acc[nt][2]+bias[nt],0.f);
        float v3 = fmaxf(acc[nt][3]+bias[nt],0.f);
        long pr = b*Ns + i0;
        pool[pr*128 + col]     = f2b((v0+v1)*0.5f);
        pool[(pr+1)*128 + col] = f2b((v2+v3)*0.5f);
      }
    }
  }
}

// -------- node nets: 64 rows/wg (4 waves x 16 rows x 128 cols), swapped MFMA --------
__global__ __launch_bounds__(256) void k_node(const short* XJ, const short* XW, const short* XT,
    const short* POOL, const short* JW1T, const short* JW2T, const float* JB1F, const float* JB2F,
    const short* WTW1T, const short* WTW2T, const float* WTB1F, const float* WTB2F,
    const float* maskf, const int* flags, void* out){
  __shared__ short hs[8192];  // 64 x 128 bf16, XOR-swizzled
  int bid = blockIdx.x;
  int net; long row0;
  if(bid < 256){ net=0; row0=(long)bid*64; }
  else if(bid < 288){ net=1; row0=(long)(bid-256)*64; }
  else { net=2; row0=(long)(bid-288)*64; }
  int NQ = (net==0) ? 4 : 3;
  int K1 = NQ*128;
  const short* X = (net==0) ? XJ : ((net==1) ? XW : XT);
  const short *P1, *P2, *P3 = nullptr;
  if(net==0){ P1=POOL; P2=POOL+2097152; P3=POOL+4194304; }
  else if(net==1){ P1=POOL+6291456; P2=POOL+6553600; }
  else { P1=POOL+6815744; P2=POOL+7077888; }
  const short* W1 = (net==0) ? JW1T : WTW1T + (long)(net-1)*49152;
  const short* W2 = (net==0) ? JW2T : WTW2T + (long)(net-1)*16384;
  const float* B1 = (net==0) ? JB1F : WTB1F + (net-1)*128;
  const float* B2 = (net==0) ? JB2F : WTB2F + (net-1)*128;
  int t = threadIdx.x, lane = t & 63, wv = t >> 6;
  int cl = lane & 15, kh = lane >> 4;
  int rl = wv*16 + cl;
  long xrow = row0 + rl;
  f32x4 acc[8] = {};
  #pragma unroll
  for(int q=0;q<4;q++){
    if(q < NQ){
      const short* SA = (q==0)?X:((q==1)?P1:((q==2)?P2:P3));
      #pragma unroll
      for(int ks=0;ks<4;ks++){
        short8 a = *(const short8*)(SA + xrow*128 + ks*32 + kh*8);
        #pragma unroll
        for(int nt=0;nt<8;nt++){
          short8 bb = *(const short8*)(W1 + (long)(nt*16 + cl)*K1 + q*128 + ks*32 + kh*8);
          acc[nt] = mfma16(bb, a, acc[nt]);   // D[w1col][xrow]
        }
      }
    }
  }
  #pragma unroll
  for(int nt=0;nt<8;nt++){
    f32x4 bv = *(const f32x4*)(B1 + nt*16 + kh*4);
    short4v sv;
    #pragma unroll
    for(int r=0;r<4;r++) sv[r] = f2b(fmaxf(acc[nt][r] + bv[r], 0.f));
    *(short4v*)((char*)hs + ((rl*256 + (nt*16 + kh*4)*2) ^ ((rl&7)<<4))) = sv;
  }
  __syncthreads();
  f32x4 acc2[8] = {};
  #pragma unroll
  for(int k0=0;k0<4;k0++){
    short8 a = *(const short8*)((const char*)hs + ((rl*256 + (k0*32 + kh*8)*2) ^ ((rl&7)<<4)));
    #pragma unroll
    for(int nt=0;nt<8;nt++){
      short8 bb = *(const short8*)(W2 + (nt*16 + cl)*128 + k0*32 + kh*8);
      acc2[nt] = mfma16(bb, a, acc2[nt]);   // D[w2col][xrow]
    }
  }
  int obf = flags[0];
  long grow = row0 + rl;
  long bbn, node; float mscale = 1.f;
  if(net==0){ bbn = grow>>4; node = grow&15; mscale = maskf[grow]; }
  else if(net==1){ bbn = grow>>1; node = 16 + (grow&1); }
  else { bbn = grow>>1; node = 18 + (grow&1); }
  long obase = (bbn*20 + node)*128;
  #pragma unroll
  for(int nt=0;nt<8;nt++){
    f32x4 bv = *(const f32x4*)(B2 + nt*16 + kh*4);
    f32x4 fv;
    #pragma unroll
    for(int r=0;r<4;r++) fv[r] = fmaxf(acc2[nt][r] + bv[r], 0.f) * mscale;
    if(obf){
      short4v sv;
      #pragma unroll
      for(int r=0;r<4;r++) sv[r] = f2b(fv[r]);
      *(short4v*)((short*)out + obase + nt*16 + kh*4) = sv;
    } else {
      *(f32x4*)((float*)out + obase + nt*16 + kh*4) = fv;
    }
  }
}

extern "C" void kernel_launch(void* const* d_in, const int* in_sizes, int n_in,
                              void* d_out, int out_size, void* d_ws, size_t ws_size,
                              hipStream_t stream){
  char* ws = (char*)d_ws;
  int*   flags  = (int*)ws;
  float* maskf  = (float*)(ws + OF_MASKF);
  float* invcnt = (float*)(ws + OF_INVCNT);
  short* XJ     = (short*)(ws + OF_XJ);
  short* XW     = (short*)(ws + OF_XW);
  short* XT     = (short*)(ws + OF_XT);
  short* W1T    = (short*)(ws + OF_W1T);
  short* W2T    = (short*)(ws + OF_W2T);
  float* EB1F   = (float*)(ws + OF_EB1F);
  float* EB2F   = (float*)(ws + OF_EB2F);
  short* JW1T   = (short*)(ws + OF_JW1T);
  short* JW2T   = (short*)(ws + OF_JW2T);
  float* JB1F   = (float*)(ws + OF_JB1F);
  float* JB2F   = (float*)(ws + OF_JB2F);
  short* WTW1T  = (short*)(ws + OF_WTW1T);
  short* WTW2T  = (short*)(ws + OF_WTW2T);
  float* WTB1F  = (float*)(ws + OF_WTB1F);
  float* WTB2F  = (float*)(ws + OF_WTB2F);
  short* POOL   = (short*)(ws + OF_POOL);

  k_probe<<<1, 64, 0, stream>>>(d_in[0], d_in[3], flags);
  k_maskbias<<<74, 256, 0, stream>>>(d_in[3], flags, maskf, invcnt,
                                     d_in[5], d_in[7], d_in[9], d_in[11], d_in[13], d_in[15],
                                     EB1F, EB2F, JB1F, JB2F, WTB1F, WTB2F);
  k_convx<<<2560, 256, 0, stream>>>(d_in[0], d_in[1], d_in[2], flags, XJ, XW, XT);
  k_trans<<<544, 256, 0, stream>>>(d_in[4], d_in[6], d_in[8], d_in[10], d_in[12], d_in[14],
                                   flags, W1T, W2T, JW1T, JW2T, WTW1T, WTW2T);
  k_fused<<<1024, 512, 0, stream>>>(XJ, XW, XT, W1T, W2T, EB1F, EB2F, maskf, invcnt, POOL);
  k_node <<<320, 256, 0, stream>>>(XJ, XW, XT, POOL, JW1T, JW2T, JB1F, JB2F,
                                   WTW1T, WTW2T, WTB1F, WTB2F, maskf, flags, d_out);
}

// Round 10
// 145.807 us; speedup vs baseline: 1.2276x; 1.2276x over previous
//
#include <hip/hip_runtime.h>
#include <hip/hip_bf16.h>

// TopoGraphLayer: B=1024, NJ=16, NW=2, NT=2, D=128, H=128
// R10 = R9 with k_proj block-decomposition bug fixed (W/T ranges were
// [384,448)/[448,512) with jp overflow; correct is 384 J + 32 W + 32 T = 448).

using short4v = __attribute__((ext_vector_type(4))) short;
using short8 = __attribute__((ext_vector_type(8))) short;
using f32x4  = __attribute__((ext_vector_type(4))) float;
using u32x4  = __attribute__((ext_vector_type(4))) unsigned;

#define DEVI __device__ __forceinline__

DEVI float b2f(short s){
  unsigned u = ((unsigned)(unsigned short)s) << 16;
  float f; __builtin_memcpy(&f, &u, 4); return f;
}
DEVI float lo16f(unsigned w){ unsigned u = w << 16; float f; __builtin_memcpy(&f,&u,4); return f; }
DEVI float hi16f(unsigned w){ unsigned u = w & 0xffff0000u; float f; __builtin_memcpy(&f,&u,4); return f; }
DEVI short f2b(float f){
  __hip_bfloat16 h = __float2bfloat16(f);
  short s; __builtin_memcpy(&s, &h, 2); return s;
}
DEVI unsigned cvtpk(float lo, float hi){
  unsigned r;
  asm("v_cvt_pk_bf16_f32 %0, %1, %2" : "=v"(r) : "v"(lo), "v"(hi));
  return r;
}
DEVI float ldflex(const void* p, long i, int bf){
  return bf ? b2f(((const short*)p)[i]) : ((const float*)p)[i];
}
DEVI f32x4 mfma16(short8 a, short8 b, f32x4 c){
  return __builtin_amdgcn_mfma_f32_16x16x32_bf16(a, b, c, 0, 0, 0);
}

// ---------------- ws byte offsets ----------------
constexpr size_t OF_MASKF  = 256;
constexpr size_t OF_INVCNT = 65792;
constexpr size_t OF_XJ     = 69888;
constexpr size_t OF_XW     = 4264192;
constexpr size_t OF_XT     = 4788480;
constexpr size_t OF_W1T    = 5312768;   // bf16 [7][128][256]
constexpr size_t OF_W2T    = 5771520;   // bf16 [7][128][128]
constexpr size_t OF_EB1F   = 6000896;
constexpr size_t OF_EB2F   = 6004480;
constexpr size_t OF_JW1T   = 6008064;   // bf16 [128][512]
constexpr size_t OF_JW2T   = 6139136;   // bf16 [128][128]
constexpr size_t OF_JB1F   = 6171904;
constexpr size_t OF_JB2F   = 6172416;
constexpr size_t OF_WTW1T  = 6172928;   // bf16 [2][128][384]
constexpr size_t OF_WTW2T  = 6369536;   // bf16 [2][128][128]
constexpr size_t OF_WTB1F  = 6435072;
constexpr size_t OF_WTB2F  = 6436096;
constexpr size_t OF_UVJ    = 6437120;   // bf16 [6][16384][128] = 25165824 B
constexpr size_t OF_UVW    = 31602944;  // bf16 [4][2048][128]  = 2097152 B
constexpr size_t OF_UVT    = 33700096;  // bf16 [4][2048][128]  = 2097152 B
constexpr size_t OF_POOL   = 65157376;  // bf16, 7,340,032 elems

// LDS UV row base per job (112 rows). J jobs p0..5=[0,1,2,4,7,11] rows p*16;
// W q0..3=[3,6,8,13] rows 96+2q; T s0..3=[5,9,10,12] rows 104+2s.
__constant__ int JOB_BASE[14] = {0,16,32,96,48,104,98,64,100,106,108,80,110,102};
// proj job tables (block order: 6 J, 4 W, 4 T)
__constant__ int QJ_NET[14]  = {0,0,1,2,3,5, 1,3,4,6, 2,4,5,6};
__constant__ int QJ_HALF[14] = {0,1,0,0,1,1, 1,0,0,1, 1,1,0,0};
// edge schedule per wave-pair
__constant__ int ES_NET[4][7] = {
 {0,0,0,0,1,1,4},
 {0,0,0,0,2,2,6},
 {0,0,0,0,3,3,0},
 {0,0,0,0,5,5,0}};
__constant__ int ES_EB[4][7] = {
 {0,16,32,48, 0,16, 0},
 {64,80,96,112, 0,16, 0},
 {128,144,160,176, 0,16, 0},
 {192,208,224,240, 0,16, 0}};
__constant__ int ES_CNT[4] = {7,7,6,6};
__constant__ int EN_LGND[7] = {4,1,1,4,1,4,1};
__constant__ int EN_NS[7]   = {16,16,16,2,2,2,2};
__constant__ long long EN_POOL[7] = {0,2097152,4194304,6291456,6553600,6815744,7077888};
// transpose jobs
__constant__ int TJ_CUM[21] = {0,32,64,96,128,160,192,224,240,256,272,288,304,320,336,400,416,464,512,528,544};
__constant__ int TJ_SEL[20] = {0,0,0,0,0,0,0,1,1,1,1,1,1,1,2,3,4,4,5,5};
__constant__ int TJ_OFF[20] = {0,32768,65536,98304,131072,163840,196608,
                               0,16384,32768,49152,65536,81920,98304,
                               0,0,0,49152,0,16384};
__constant__ int TJ_R[20]   = {256,256,256,256,256,256,256,128,128,128,128,128,128,128,512,128,384,384,128,128};

// -------- probe: detect float dtype (f32 vs bf16) and mask format --------
__global__ __launch_bounds__(64) void k_probe(const void* jets, const void* mask, int* flags){
  int l = threadIdx.x;
  int extreme = 0;
  #pragma unroll
  for(int s=0;s<4;s++){
    unsigned short v = ((const unsigned short*)jets)[(l*4+s)*2];
    int e = (v>>7)&0xff;
    if(e<110||e>140) extreme++;
  }
  #pragma unroll
  for(int o=1;o<64;o<<=1) extreme += __shfl_xor(extreme, o);
  bool all01=true, allf32=true;
  #pragma unroll
  for(int s=0;s<4;s++){
    unsigned w = ((const unsigned*)mask)[l*4+s];
    if(w>1u) all01=false;
    if(w!=0u && w!=0x3F800000u) allf32=false;
  }
  bool allbfv=true; int evnz=0;
  #pragma unroll
  for(int s=0;s<8;s++){
    unsigned short v = ((const unsigned short*)mask)[l*8+s];
    if(v!=0&&v!=0x3F80) allbfv=false;
    if(((l*8+s)&1)==0 && v!=0) evnz++;
  }
  #pragma unroll
  for(int o=1;o<64;o<<=1) evnz += __shfl_xor(evnz, o);
  bool allb01=true;
  #pragma unroll
  for(int s=0;s<16;s++){ if(((const unsigned char*)mask)[l*16+s]>1) allb01=false; }
  int a01 = __all(all01), af32 = __all(allf32), abf = __all(allbfv), ab01 = __all(allb01);
  if(l==0){
    flags[0] = (extreme <= 32) ? 1 : 0;   // 1=bf16 inputs, 0=f32
    int fmt = 0;
    if(a01) fmt=0; else if(abf && evnz>0) fmt=2; else if(af32) fmt=3; else if(ab01) fmt=1;
    flags[1] = fmt;
  }
}

// -------- maskf + invcnt + biases (merged) --------
__global__ __launch_bounds__(256) void k_maskbias(const void* mask, const int* flags,
    float* maskf, float* invcnt,
    const void* eb1, const void* eb2, const void* jb1, const void* jb2,
    const void* wb1, const void* wb2,
    float* EB1F, float* EB2F, float* JB1F, float* JB2F, float* WTB1F, float* WTB2F){
  int bid = blockIdx.x;
  if(bid < 64){
    int t = bid*256 + threadIdx.x;  // 0..16383
    int fmt = flags[1];
    float m;
    if(fmt==0)      m = (((const int*)mask)[t]!=0) ? 1.f : 0.f;
    else if(fmt==1) m = (((const unsigned char*)mask)[t]!=0) ? 1.f : 0.f;
    else if(fmt==2) m = (b2f(((const short*)mask)[t])!=0.f) ? 1.f : 0.f;
    else            m = (((const float*)mask)[t]!=0.f) ? 1.f : 0.f;
    maskf[t] = m;
    float s = m;
    for(int o=1;o<16;o<<=1) s += __shfl_xor(s, o);
    if((t&15)==0) invcnt[t>>4] = 1.f / fmaxf(s, 1.f);
  } else {
    int id = (bid-64)*256 + threadIdx.x;
    int bf = flags[0];
    if(id<896)        EB1F[id]       = ldflex(eb1, id, bf);
    else if(id<1792)  EB2F[id-896]   = ldflex(eb2, id-896, bf);
    else if(id<1920)  JB1F[id-1792]  = ldflex(jb1, id-1792, bf);
    else if(id<2048)  JB2F[id-1920]  = ldflex(jb2, id-1920, bf);
    else if(id<2304)  WTB1F[id-2048] = ldflex(wb1, id-2048, bf);
    else if(id<2560)  WTB2F[id-2304] = ldflex(wb2, id-2304, bf);
  }
}

// -------- convert node inputs to canonical bf16 (x4 vectorized) --------
__global__ __launch_bounds__(256) void k_convx(const void* jets, const void* nw, const void* nt,
                                               const int* flags, short* XJ, short* XW, short* XT){
  long i = ((long)blockIdx.x*256 + threadIdx.x)*4;
  int bf = flags[0];
  const void* src; short* dst; long o;
  if(i < 2097152){ src=jets; dst=XJ; o=i; }
  else if(i < 2359296){ src=nw; dst=XW; o=i-2097152; }
  else { src=nt; dst=XT; o=i-2359296; }
  short4v r;
  if(bf){
    r = *(const short4v*)((const short*)src + o);
  } else {
    f32x4 v = *(const f32x4*)((const float*)src + o);
    #pragma unroll
    for(int e=0;e<4;e++) r[e] = f2b(v[e]);
  }
  *(short4v*)(dst + o) = r;
}

// -------- weight transpose via LDS 32x32 tiles --------
__global__ __launch_bounds__(256) void k_trans(const void* eW1, const void* eW2, const void* jW1,
    const void* jW2, const void* wW1, const void* wW2, const int* flags,
    short* W1T, short* W2T, short* JW1T, short* JW2T, short* WTW1T, short* WTW2T){
  __shared__ float tl[32][33];
  int tile = blockIdx.x; int job = 0;
  while(tile >= TJ_CUM[job+1]) job++;
  tile -= TJ_CUM[job];
  int sel = TJ_SEL[job]; long off = TJ_OFF[job]; int R = TJ_R[job];
  int bf = flags[0];
  const void* src = sel==0?eW1: sel==1?eW2: sel==2?jW1: sel==3?jW2: sel==4?wW1: wW2;
  short* dst = sel==0?W1T: sel==1?W2T: sel==2?JW1T: sel==3?JW2T: sel==4?WTW1T: WTW2T;
  int tr = (tile>>2)*32, tc = (tile&3)*32;
  int t = threadIdx.x, r = t>>3, c4 = (t&7)*4;
  #pragma unroll
  for(int j=0;j<4;j++) tl[r][c4+j] = ldflex(src, off + (long)(tr+r)*128 + tc + c4 + j, bf);
  __syncthreads();
  short4v o;
  #pragma unroll
  for(int j=0;j<4;j++) o[j] = f2b(tl[c4+j][r]);
  *(short4v*)(dst + off + (long)(tc+r)*R + tr + c4) = o;
}

// -------- projections as 3 dense GEMMs; output p-major bf16 --------
// block = 256 rows x 128 cols (one job p). J: 6x64 blocks, W: 4x8, T: 4x8. Grid 448.
__global__ __launch_bounds__(512, 4) void k_proj(const short* XJ, const short* XW, const short* XT,
    const short* W1T, const float* EB1F, short* UVJ, short* UVW, short* UVT){
  int bid = blockIdx.x;
  int jp, rb; const short* X; short* out;
  if(bid < 384){ jp = bid>>6; rb = bid&63; X=XJ; out=UVJ + jp*2097152; }
  else if(bid < 416){ int r2=bid-384; jp = 6 + (r2>>3); rb = r2&7; X=XW; out=UVW + (jp-6)*262144; }
  else { int r2=bid-416; jp = 10 + (r2>>3); rb = r2&7; X=XT; out=UVT + (jp-10)*262144; }
  int net = QJ_NET[jp], half = QJ_HALF[jp];
  bool addb = (half==0);
  long row0 = (long)rb * 256;
  const short* Wb = W1T + net*32768 + half*128;
  int t = threadIdx.x, lane = t & 63, wv = t >> 6;
  int rbw = wv >> 1, ch = (wv & 1)*64;
  int cl = lane & 15, kh = lane >> 4;
  short8 bw[4][4];
  f32x4 biasv[4];
  #pragma unroll
  for(int nt=0;nt<4;nt++){
    #pragma unroll
    for(int ks=0;ks<4;ks++)
      bw[nt][ks] = *(const short8*)(Wb + (ch + nt*16 + cl)*256 + ks*32 + kh*8);
    if(addb) biasv[nt] = *(const f32x4*)(EB1F + net*128 + ch + nt*16 + kh*4);
    else     biasv[nt] = f32x4{0.f,0.f,0.f,0.f};
  }
  #pragma unroll 1
  for(int c=0;c<4;c++){
    long T0 = row0 + c*64 + rbw*16;
    short8 a[4];
    #pragma unroll
    for(int ks=0;ks<4;ks++)
      a[ks] = *(const short8*)(X + (T0 + cl)*128 + ks*32 + kh*8);
    f32x4 acc[4] = {};
    #pragma unroll
    for(int ks=0;ks<4;ks++)
      #pragma unroll
      for(int nt=0;nt<4;nt++)
        acc[nt] = mfma16(bw[nt][ks], a[ks], acc[nt]);   // D: col=xrow(cl), row=wcol
    #pragma unroll
    for(int nt=0;nt<4;nt++){
      short4v sv;
      #pragma unroll
      for(int r=0;r<4;r++) sv[r] = f2b(acc[nt][r] + biasv[nt][r]);
      *(short4v*)(out + (T0 + cl)*128 + ch + nt*16 + kh*4) = sv;
    }
  }
}

// -------- edge: stage batch UV -> LDS f32, then edge layer2 + pool --------
__global__ __launch_bounds__(512, 4) void k_edge(const short* UVJ, const short* UVW, const short* UVT,
    const short* W2T, const float* EB2F, const float* maskf, const float* invcnt, short* POOL){
  __shared__ float UVs[14336];   // 112 x 128 f32 = 57,344 B, swz byte^=(row&7)<<4
  long b = blockIdx.x;
  int t = threadIdx.x, lane = t & 63, wv = t >> 6;
  int pair = wv >> 1, h = wv & 1;
  int cl = lane & 15, kh = lane >> 4;

  // ---- stage: 1792 16B-chunks (row = c>>4, blk = c&15) ----
  int nc = (t < 256) ? 4 : 3;
  for(int ci=0; ci<nc; ci++){
    int c = t + ci*512;
    int row = c >> 4, blk = c & 15;
    const short* src;
    if(row < 96){
      int p = row >> 4, i = row & 15;
      src = UVJ + (p*16384 + b*16 + i)*128;
    } else if(row < 104){
      int q = (row-96) >> 1, w = (row-96) & 1;
      src = UVW + (q*2048 + b*2 + w)*128;
    } else {
      int s = (row-104) >> 1, tt = (row-104) & 1;
      src = UVT + (s*2048 + b*2 + tt)*128;
    }
    u32x4 w4 = *(const u32x4*)(src + blk*8);
    int base = row*512 + blk*32, swz = (row&7)<<4;
    f32x4 f0, f1;
    f0[0]=lo16f(w4[0]); f0[1]=hi16f(w4[0]); f0[2]=lo16f(w4[1]); f0[3]=hi16f(w4[1]);
    f1[0]=lo16f(w4[2]); f1[1]=hi16f(w4[2]); f1[2]=lo16f(w4[3]); f1[3]=hi16f(w4[3]);
    *(f32x4*)((char*)UVs + (base ^ swz)) = f0;
    *(f32x4*)((char*)UVs + ((base+16) ^ swz)) = f1;
  }
  __syncthreads();

  // ---- edge + pool (verified R8 structure, new JOB_BASE) ----
  int prevnet = -1;
  short8 bw[4][4];
  float bias[4];
  int cnt = ES_CNT[pair];
  for(int slot=0; slot<cnt; slot++){
    int net = ES_NET[pair][slot];
    int eb  = ES_EB[pair][slot];
    if(net != prevnet){
      const short* Wb2 = W2T + net*16384;
      #pragma unroll
      for(int nt=0;nt<4;nt++){
        #pragma unroll
        for(int ks=0;ks<4;ks++)
          bw[nt][ks] = *(const short8*)(Wb2 + (h*64 + nt*16 + cl)*128 + ks*32 + kh*8);
        bias[nt] = EB2F[net*128 + h*64 + nt*16 + cl];
      }
      prevnet = net;
    }
    int lgNd = EN_LGND[net];
    int tiny = (net==4) | (net==6);
    int sj = JOB_BASE[2*net], dj = JOB_BASE[2*net+1];
    int e = tiny ? (cl&3) : (eb + cl);
    int urow = sj + (e >> lgNd);
    int vrow = dj + (e & ((1<<lgNd)-1));
    int uswz = (urow&7)<<4, vswz = (vrow&7)<<4;
    f32x4 acc[4] = {};
    #pragma unroll
    for(int ks=0;ks<4;ks++){
      int ubase = urow*512 + ks*128 + kh*32;
      int vbase = vrow*512 + ks*128 + kh*32;
      f32x4 u0 = *(const f32x4*)((const char*)UVs + (ubase ^ uswz));
      f32x4 u1 = *(const f32x4*)((const char*)UVs + ((ubase+16) ^ uswz));
      f32x4 v0 = *(const f32x4*)((const char*)UVs + (vbase ^ vswz));
      f32x4 v1 = *(const f32x4*)((const char*)UVs + ((vbase+16) ^ vswz));
      u32x4 aw;
      aw[0] = cvtpk(fmaxf(u0[0]+v0[0],0.f), fmaxf(u0[1]+v0[1],0.f));
      aw[1] = cvtpk(fmaxf(u0[2]+v0[2],0.f), fmaxf(u0[3]+v0[3],0.f));
      aw[2] = cvtpk(fmaxf(u1[0]+v1[0],0.f), fmaxf(u1[1]+v1[1],0.f));
      aw[3] = cvtpk(fmaxf(u1[2]+v1[2],0.f), fmaxf(u1[3]+v1[3],0.f));
      short8 a = __builtin_bit_cast(short8, aw);
      #pragma unroll
      for(int nt=0;nt<4;nt++)
        acc[nt] = mfma16(a, bw[nt][ks], acc[nt]);   // D: row=edge row, col=w2 col
    }
    short* pool = POOL + EN_POOL[net];
    int Ns = EN_NS[net];
    if(tiny){
      if(kh == 0){
        #pragma unroll
        for(int nt=0;nt<4;nt++){
          int col = h*64 + nt*16 + cl;
          float v0 = fmaxf(acc[nt][0]+bias[nt],0.f);
          float v1 = fmaxf(acc[nt][1]+bias[nt],0.f);
          float v2 = fmaxf(acc[nt][2]+bias[nt],0.f);
          float v3 = fmaxf(acc[nt][3]+bias[nt],0.f);
          long pr = b*2;
          pool[pr*128 + col]     = f2b((v0+v1)*0.5f);
          pool[(pr+1)*128 + col] = f2b((v2+v3)*0.5f);
        }
      }
    } else if(lgNd == 4){
      float ic = invcnt[b];
      float wr[4];
      #pragma unroll
      for(int r=0;r<4;r++)
        wr[r] = maskf[b*16 + kh*4 + r] * ic;
      #pragma unroll
      for(int nt=0;nt<4;nt++){
        int col = h*64 + nt*16 + cl;
        float s = fmaxf(acc[nt][0]+bias[nt],0.f)*wr[0]
                + fmaxf(acc[nt][1]+bias[nt],0.f)*wr[1]
                + fmaxf(acc[nt][2]+bias[nt],0.f)*wr[2]
                + fmaxf(acc[nt][3]+bias[nt],0.f)*wr[3];
        s += __shfl_xor(s, 16);
        s += __shfl_xor(s, 32);
        if(lane < 16)
          pool[(b*Ns + (eb>>4))*128 + col] = f2b(s);
      }
    } else {
      long i0 = (eb + kh*4) >> 1;
      #pragma unroll
      for(int nt=0;nt<4;nt++){
        int col = h*64 + nt*16 + cl;
        float v0 = fmaxf(acc[nt][0]+bias[nt],0.f);
        float v1 = fmaxf(acc[nt][1]+bias[nt],0.f);
        float v2 = fmaxf(acc[nt][2]+bias[nt],0.f);
        float v3 = fmaxf(acc[nt][3]+bias[nt],0.f);
        long pr = b*Ns + i0;
        pool[pr*128 + col]     = f2b((v0+v1)*0.5f);
        pool[(pr+1)*128 + col] = f2b((v2+v3)*0.5f);
      }
    }
  }
}

// -------- node nets: 64 rows/wg (4 waves x 16 rows x 128 cols), swapped MFMA --------
__global__ __launch_bounds__(256) void k_node(const short* XJ, const short* XW, const short* XT,
    const short* POOL, const short* JW1T, const short* JW2T, const float* JB1F, const float* JB2F,
    const short* WTW1T, const short* WTW2T, const float* WTB1F, const float* WTB2F,
    const float* maskf, const int* flags, void* out){
  __shared__ short hs[8192];  // 64 x 128 bf16, XOR-swizzled
  int bid = blockIdx.x;
  int net; long row0;
  if(bid < 256){ net=0; row0=(long)bid*64; }
  else if(bid < 288){ net=1; row0=(long)(bid-256)*64; }
  else { net=2; row0=(long)(bid-288)*64; }
  int NQ = (net==0) ? 4 : 3;
  int K1 = NQ*128;
  const short* X = (net==0) ? XJ : ((net==1) ? XW : XT);
  const short *P1, *P2, *P3 = nullptr;
  if(net==0){ P1=POOL; P2=POOL+2097152; P3=POOL+4194304; }
  else if(net==1){ P1=POOL+6291456; P2=POOL+6553600; }
  else { P1=POOL+6815744; P2=POOL+7077888; }
  const short* W1 = (net==0) ? JW1T : WTW1T + (long)(net-1)*49152;
  const short* W2 = (net==0) ? JW2T : WTW2T + (long)(net-1)*16384;
  const float* B1 = (net==0) ? JB1F : WTB1F + (net-1)*128;
  const float* B2 = (net==0) ? JB2F : WTB2F + (net-1)*128;
  int t = threadIdx.x, lane = t & 63, wv = t >> 6;
  int cl = lane & 15, kh = lane >> 4;
  int rl = wv*16 + cl;
  long xrow = row0 + rl;
  f32x4 acc[8] = {};
  #pragma unroll
  for(int q=0;q<4;q++){
    if(q < NQ){
      const short* SA = (q==0)?X:((q==1)?P1:((q==2)?P2:P3));
      #pragma unroll
      for(int ks=0;ks<4;ks++){
        short8 a = *(const short8*)(SA + xrow*128 + ks*32 + kh*8);
        #pragma unroll
        for(int nt=0;nt<8;nt++){
          short8 bb = *(const short8*)(W1 + (long)(nt*16 + cl)*K1 + q*128 + ks*32 + kh*8);
          acc[nt] = mfma16(bb, a, acc[nt]);   // D[w1col][xrow]
        }
      }
    }
  }
  #pragma unroll
  for(int nt=0;nt<8;nt++){
    f32x4 bv = *(const f32x4*)(B1 + nt*16 + kh*4);
    short4v sv;
    #pragma unroll
    for(int r=0;r<4;r++) sv[r] = f2b(fmaxf(acc[nt][r] + bv[r], 0.f));
    *(short4v*)((char*)hs + ((rl*256 + (nt*16 + kh*4)*2) ^ ((rl&7)<<4))) = sv;
  }
  __syncthreads();
  f32x4 acc2[8] = {};
  #pragma unroll
  for(int k0=0;k0<4;k0++){
    short8 a = *(const short8*)((const char*)hs + ((rl*256 + (k0*32 + kh*8)*2) ^ ((rl&7)<<4)));
    #pragma unroll
    for(int nt=0;nt<8;nt++){
      short8 bb = *(const short8*)(W2 + (nt*16 + cl)*128 + k0*32 + kh*8);
      acc2[nt] = mfma16(bb, a, acc2[nt]);   // D[w2col][xrow]
    }
  }
  int obf = flags[0];
  long grow = row0 + rl;
  long bbn, node; float mscale = 1.f;
  if(net==0){ bbn = grow>>4; node = grow&15; mscale = maskf[grow]; }
  else if(net==1){ bbn = grow>>1; node = 16 + (grow&1); }
  else { bbn = grow>>1; node = 18 + (grow&1); }
  long obase = (bbn*20 + node)*128;
  #pragma unroll
  for(int nt=0;nt<8;nt++){
    f32x4 bv = *(const f32x4*)(B2 + nt*16 + kh*4);
    f32x4 fv;
    #pragma unroll
    for(int r=0;r<4;r++) fv[r] = fmaxf(acc2[nt][r] + bv[r], 0.f) * mscale;
    if(obf){
      short4v sv;
      #pragma unroll
      for(int r=0;r<4;r++) sv[r] = f2b(fv[r]);
      *(short4v*)((short*)out + obase + nt*16 + kh*4) = sv;
    } else {
      *(f32x4*)((float*)out + obase + nt*16 + kh*4) = fv;
    }
  }
}

extern "C" void kernel_launch(void* const* d_in, const int* in_sizes, int n_in,
                              void* d_out, int out_size, void* d_ws, size_t ws_size,
                              hipStream_t stream){
  char* ws = (char*)d_ws;
  int*   flags  = (int*)ws;
  float* maskf  = (float*)(ws + OF_MASKF);
  float* invcnt = (float*)(ws + OF_INVCNT);
  short* XJ     = (short*)(ws + OF_XJ);
  short* XW     = (short*)(ws + OF_XW);
  short* XT     = (short*)(ws + OF_XT);
  short* W1T    = (short*)(ws + OF_W1T);
  short* W2T    = (short*)(ws + OF_W2T);
  float* EB1F   = (float*)(ws + OF_EB1F);
  float* EB2F   = (float*)(ws + OF_EB2F);
  short* JW1T   = (short*)(ws + OF_JW1T);
  short* JW2T   = (short*)(ws + OF_JW2T);
  float* JB1F   = (float*)(ws + OF_JB1F);
  float* JB2F   = (float*)(ws + OF_JB2F);
  short* WTW1T  = (short*)(ws + OF_WTW1T);
  short* WTW2T  = (short*)(ws + OF_WTW2T);
  float* WTB1F  = (float*)(ws + OF_WTB1F);
  float* WTB2F  = (float*)(ws + OF_WTB2F);
  short* UVJ    = (short*)(ws + OF_UVJ);
  short* UVW    = (short*)(ws + OF_UVW);
  short* UVT    = (short*)(ws + OF_UVT);
  short* POOL   = (short*)(ws + OF_POOL);

  k_probe<<<1, 64, 0, stream>>>(d_in[0], d_in[3], flags);
  k_maskbias<<<74, 256, 0, stream>>>(d_in[3], flags, maskf, invcnt,
                                     d_in[5], d_in[7], d_in[9], d_in[11], d_in[13], d_in[15],
                                     EB1F, EB2F, JB1F, JB2F, WTB1F, WTB2F);
  k_convx<<<2560, 256, 0, stream>>>(d_in[0], d_in[1], d_in[2], flags, XJ, XW, XT);
  k_trans<<<544, 256, 0, stream>>>(d_in[4], d_in[6], d_in[8], d_in[10], d_in[12], d_in[14],
                                   flags, W1T, W2T, JW1T, JW2T, WTW1T, WTW2T);
  k_proj <<<448, 512, 0, stream>>>(XJ, XW, XT, W1T, EB1F, UVJ, UVW, UVT);
  k_edge <<<1024, 512, 0, stream>>>(UVJ, UVW, UVT, W2T, EB2F, maskf, invcnt, POOL);
  k_node <<<320, 256, 0, stream>>>(XJ, XW, XT, POOL, JW1T, JW2T, JB1F, JB2F,
                                   WTW1T, WTW2T, WTB1F, WTB2F, maskf, flags, d_out);
}